// Round 1
// baseline (155.915 us; speedup 1.0000x reference)
//
#include <hip/hip_runtime.h>
#include <cmath>

#define TPB 4          // tokens per block
#define SCALEF 8.0f    // alpha/rank = 32/4

__global__ __launch_bounds__(256, 4) void tmlora_fused(
    const float* __restrict__ x,
    const float* __restrict__ A_w,
    const float* __restrict__ B_w,
    const float* __restrict__ router_w,
    const float* __restrict__ expert_vectors,
    float* __restrict__ out)
{
    const int tid  = threadIdx.x;
    const int tok0 = blockIdx.x * TPB;

    const float4* __restrict__ x4 = (const float4*)x;          // [ntok][1024]
    const float4* __restrict__ r4 = (const float4*)router_w;   // [8][1024]
    const float4* __restrict__ a4 = (const float4*)A_w;        // [4][1024]

    // ---- Phase 1: 12 dot products per token, block-cooperative ----
    float acc[TPB][12];
#pragma unroll
    for (int tk = 0; tk < TPB; ++tk)
#pragma unroll
        for (int w = 0; w < 12; ++w) acc[tk][w] = 0.f;

#pragma unroll
    for (int p = 0; p < 4; ++p) {
        const int c = p * 256 + tid;      // float4 column index 0..1023
        float4 xv[TPB];
#pragma unroll
        for (int tk = 0; tk < TPB; ++tk)
            xv[tk] = x4[(size_t)(tok0 + tk) * 1024 + c];

#pragma unroll
        for (int e = 0; e < 8; ++e) {
            const float4 wv = r4[e * 1024 + c];
#pragma unroll
            for (int tk = 0; tk < TPB; ++tk) {
                acc[tk][e] = fmaf(xv[tk].x, wv.x, acc[tk][e]);
                acc[tk][e] = fmaf(xv[tk].y, wv.y, acc[tk][e]);
                acc[tk][e] = fmaf(xv[tk].z, wv.z, acc[tk][e]);
                acc[tk][e] = fmaf(xv[tk].w, wv.w, acc[tk][e]);
            }
        }
#pragma unroll
        for (int r = 0; r < 4; ++r) {
            const float4 wv = a4[r * 1024 + c];
#pragma unroll
            for (int tk = 0; tk < TPB; ++tk) {
                acc[tk][8 + r] = fmaf(xv[tk].x, wv.x, acc[tk][8 + r]);
                acc[tk][8 + r] = fmaf(xv[tk].y, wv.y, acc[tk][8 + r]);
                acc[tk][8 + r] = fmaf(xv[tk].z, wv.z, acc[tk][8 + r]);
                acc[tk][8 + r] = fmaf(xv[tk].w, wv.w, acc[tk][8 + r]);
            }
        }
    }

    // ---- wave butterfly reduction (all lanes end with wave sum) ----
#pragma unroll
    for (int tk = 0; tk < TPB; ++tk)
#pragma unroll
        for (int w = 0; w < 12; ++w) {
            float v = acc[tk][w];
#pragma unroll
            for (int m = 1; m < 64; m <<= 1) v += __shfl_xor(v, m, 64);
            acc[tk][w] = v;
        }

    __shared__ float red[4][TPB * 12];
    __shared__ float hsh[TPB][4];
    const int wid = tid >> 6, lane = tid & 63;
    if (lane == 0) {
#pragma unroll
        for (int tk = 0; tk < TPB; ++tk)
#pragma unroll
            for (int w = 0; w < 12; ++w) red[wid][tk * 12 + w] = acc[tk][w];
    }
    __syncthreads();

    // ---- scalar epilogue: top-4 / softmax / expert mix / exact gelu ----
    if (tid < TPB) {
        const int tk = tid;
        float s12[12];
#pragma unroll
        for (int w = 0; w < 12; ++w)
            s12[w] = red[0][tk * 12 + w] + red[1][tk * 12 + w] +
                     red[2][tk * 12 + w] + red[3][tk * 12 + w];

        float sc[8];
#pragma unroll
        for (int e = 0; e < 8; ++e) sc[e] = s12[e];

        int   idx[4];
        float val[4];
#pragma unroll
        for (int k = 0; k < 4; ++k) {
            int bi = 0; float bv = sc[0];
#pragma unroll
            for (int e = 1; e < 8; ++e) {
                if (sc[e] > bv) { bv = sc[e]; bi = e; }
            }
            idx[k] = bi; val[k] = bv;
            // knock out winner without runtime-indexed local store (no scratch)
#pragma unroll
            for (int e = 0; e < 8; ++e)
                if (e == bi) sc[e] = -INFINITY;
        }

        const float mx = val[0];   // sorted descending
        float ex[4], se = 0.f;
#pragma unroll
        for (int k = 0; k < 4; ++k) { ex[k] = expf(val[k] - mx); se += ex[k]; }
        const float inv = 1.f / se;

        float Et[4] = {0.f, 0.f, 0.f, 0.f};
#pragma unroll
        for (int k = 0; k < 4; ++k) {
            const float wgt = ex[k] * inv;
#pragma unroll
            for (int r = 0; r < 4; ++r)
                Et[r] = fmaf(wgt, expert_vectors[idx[k] * 4 + r], Et[r]);
        }
#pragma unroll
        for (int r = 0; r < 4; ++r) {
            const float h = s12[8 + r] + Et[r];
            const float g = 0.5f * h * (1.f + erff(h * 0.70710678118654752f));
            hsh[tk][r] = g;
        }
    }

    // ---- Phase 2: cache B_w rows in registers (acc now dead) ----
    float4 Bc[4][4];
    const float4* __restrict__ b4 = (const float4*)B_w;   // row o = float4 o
#pragma unroll
    for (int i = 0; i < 4; ++i)
#pragma unroll
        for (int k = 0; k < 4; ++k)
            Bc[i][k] = b4[4 * (i * 256 + tid) + k];

    __syncthreads();

#pragma unroll
    for (int tk = 0; tk < TPB; ++tk) {
        const float h0 = hsh[tk][0], h1 = hsh[tk][1],
                    h2 = hsh[tk][2], h3 = hsh[tk][3];
        float4* __restrict__ o4 = (float4*)out + (size_t)(tok0 + tk) * 1024;
#pragma unroll
        for (int i = 0; i < 4; ++i) {
            float4 v;
            v.x = SCALEF * (Bc[i][0].x * h0 + Bc[i][0].y * h1 + Bc[i][0].z * h2 + Bc[i][0].w * h3);
            v.y = SCALEF * (Bc[i][1].x * h0 + Bc[i][1].y * h1 + Bc[i][1].z * h2 + Bc[i][1].w * h3);
            v.z = SCALEF * (Bc[i][2].x * h0 + Bc[i][2].y * h1 + Bc[i][2].z * h2 + Bc[i][2].w * h3);
            v.w = SCALEF * (Bc[i][3].x * h0 + Bc[i][3].y * h1 + Bc[i][3].z * h2 + Bc[i][3].w * h3);
            o4[i * 256 + tid] = v;
        }
    }
}

extern "C" void kernel_launch(void* const* d_in, const int* in_sizes, int n_in,
                              void* d_out, int out_size, void* d_ws, size_t ws_size,
                              hipStream_t stream) {
    const float* x        = (const float*)d_in[0];
    const float* A_w      = (const float*)d_in[1];
    const float* B_w      = (const float*)d_in[2];
    const float* router_w = (const float*)d_in[3];
    const float* ev       = (const float*)d_in[4];
    float* out            = (float*)d_out;

    const int ntok = in_sizes[0] / 4096;     // B*S = 16384
    const int grid = ntok / TPB;             // 4096 blocks
    tmlora_fused<<<grid, 256, 0, stream>>>(x, A_w, B_w, router_w, ev, out);
}

// Round 2
// 142.270 us; speedup vs baseline: 1.0959x; 1.0959x over previous
//
#include <hip/hip_runtime.h>
#include <cmath>

#define TPB 4          // tokens per block
#define SCALEF 8.0f    // alpha/rank = 32/4

__global__ __launch_bounds__(256, 3) void tmlora_fused(
    const float* __restrict__ x,
    const float* __restrict__ A_w,
    const float* __restrict__ B_w,
    const float* __restrict__ router_w,
    const float* __restrict__ expert_vectors,
    float* __restrict__ out)
{
    const int tid  = threadIdx.x;
    const int tok0 = blockIdx.x * TPB;

    const float4* __restrict__ x4 = (const float4*)x;          // [ntok][1024]
    const float4* __restrict__ r4 = (const float4*)router_w;   // [8][1024]
    const float4* __restrict__ a4 = (const float4*)A_w;        // [4][1024]

    // ---- Phase 1: hoist ALL x loads (16 independent HBM loads in flight) ----
    float4 xv[4][TPB];   // [p][token]
#pragma unroll
    for (int p = 0; p < 4; ++p)
#pragma unroll
        for (int tk = 0; tk < TPB; ++tk)
            xv[p][tk] = x4[(size_t)(tok0 + tk) * 1024 + p * 256 + tid];

    float acc[TPB][12];
#pragma unroll
    for (int tk = 0; tk < TPB; ++tk)
#pragma unroll
        for (int w = 0; w < 12; ++w) acc[tk][w] = 0.f;

    // ---- weight stream, 2-deep software pipeline (w and w+1 in flight) ----
    float4 wbuf[2][4];   // [parity][p] — all indices compile-time (w unrolled)
#pragma unroll
    for (int p = 0; p < 4; ++p)
        wbuf[0][p] = r4[p * 256 + tid];            // w = 0

#pragma unroll
    for (int w = 0; w < 12; ++w) {
        const int cur = w & 1, nxt = cur ^ 1;
        if (w < 11) {
            const float4* __restrict__ src =
                (w + 1 < 8) ? (r4 + (size_t)(w + 1) * 1024)
                            : (a4 + (size_t)(w + 1 - 8) * 1024);
#pragma unroll
            for (int p = 0; p < 4; ++p)
                wbuf[nxt][p] = src[p * 256 + tid];
        }
#pragma unroll
        for (int p = 0; p < 4; ++p) {
            const float4 wv = wbuf[cur][p];
#pragma unroll
            for (int tk = 0; tk < TPB; ++tk) {
                acc[tk][w] = fmaf(xv[p][tk].x, wv.x, acc[tk][w]);
                acc[tk][w] = fmaf(xv[p][tk].y, wv.y, acc[tk][w]);
                acc[tk][w] = fmaf(xv[p][tk].z, wv.z, acc[tk][w]);
                acc[tk][w] = fmaf(xv[p][tk].w, wv.w, acc[tk][w]);
            }
        }
    }

    // ---- Phase 2 prefetch: issue B_w loads now; latency hides under reduce ----
    float4 Bc[4][4];
    const float4* __restrict__ b4 = (const float4*)B_w;   // row o = one float4
#pragma unroll
    for (int i = 0; i < 4; ++i)
#pragma unroll
        for (int k = 0; k < 4; ++k)
            Bc[i][k] = b4[4 * (i * 256 + tid) + k];

    // ---- wave butterfly reduction ----
#pragma unroll
    for (int tk = 0; tk < TPB; ++tk)
#pragma unroll
        for (int w = 0; w < 12; ++w) {
            float v = acc[tk][w];
#pragma unroll
            for (int m = 1; m < 64; m <<= 1) v += __shfl_xor(v, m, 64);
            acc[tk][w] = v;
        }

    __shared__ float red[4][TPB * 12];
    __shared__ float hsh[TPB][4];
    const int wid = tid >> 6, lane = tid & 63;
    if (lane == 0) {
#pragma unroll
        for (int tk = 0; tk < TPB; ++tk)
#pragma unroll
            for (int w = 0; w < 12; ++w) red[wid][tk * 12 + w] = acc[tk][w];
    }
    __syncthreads();

    // ---- scalar epilogue: top-4 / softmax / expert mix / exact gelu ----
    if (tid < TPB) {
        const int tk = tid;
        float s12[12];
#pragma unroll
        for (int w = 0; w < 12; ++w)
            s12[w] = red[0][tk * 12 + w] + red[1][tk * 12 + w] +
                     red[2][tk * 12 + w] + red[3][tk * 12 + w];

        float sc[8];
#pragma unroll
        for (int e = 0; e < 8; ++e) sc[e] = s12[e];

        int   idx[4];
        float val[4];
#pragma unroll
        for (int k = 0; k < 4; ++k) {
            int bi = 0; float bv = sc[0];
#pragma unroll
            for (int e = 1; e < 8; ++e) {
                if (sc[e] > bv) { bv = sc[e]; bi = e; }
            }
            idx[k] = bi; val[k] = bv;
#pragma unroll
            for (int e = 0; e < 8; ++e)
                if (e == bi) sc[e] = -INFINITY;   // static-index knockout
        }

        const float mx = val[0];   // descending order
        float ex[4], se = 0.f;
#pragma unroll
        for (int k = 0; k < 4; ++k) { ex[k] = expf(val[k] - mx); se += ex[k]; }
        const float inv = 1.f / se;

        float Et[4] = {0.f, 0.f, 0.f, 0.f};
#pragma unroll
        for (int k = 0; k < 4; ++k) {
            const float wgt = ex[k] * inv;
#pragma unroll
            for (int r = 0; r < 4; ++r)
                Et[r] = fmaf(wgt, expert_vectors[idx[k] * 4 + r], Et[r]);
        }
#pragma unroll
        for (int r = 0; r < 4; ++r) {
            const float h = s12[8 + r] + Et[r];
            const float g = 0.5f * h * (1.f + erff(h * 0.70710678118654752f));
            hsh[tk][r] = g;
        }
    }

    __syncthreads();

    // ---- Phase 2: out rows = h · B^T, B cached in VGPRs ----
#pragma unroll
    for (int tk = 0; tk < TPB; ++tk) {
        const float h0 = hsh[tk][0], h1 = hsh[tk][1],
                    h2 = hsh[tk][2], h3 = hsh[tk][3];
        float4* __restrict__ o4 = (float4*)out + (size_t)(tok0 + tk) * 1024;
#pragma unroll
        for (int i = 0; i < 4; ++i) {
            float4 v;
            v.x = SCALEF * (Bc[i][0].x * h0 + Bc[i][0].y * h1 + Bc[i][0].z * h2 + Bc[i][0].w * h3);
            v.y = SCALEF * (Bc[i][1].x * h0 + Bc[i][1].y * h1 + Bc[i][1].z * h2 + Bc[i][1].w * h3);
            v.z = SCALEF * (Bc[i][2].x * h0 + Bc[i][2].y * h1 + Bc[i][2].z * h2 + Bc[i][2].w * h3);
            v.w = SCALEF * (Bc[i][3].x * h0 + Bc[i][3].y * h1 + Bc[i][3].z * h2 + Bc[i][3].w * h3);
            o4[i * 256 + tid] = v;
        }
    }
}

extern "C" void kernel_launch(void* const* d_in, const int* in_sizes, int n_in,
                              void* d_out, int out_size, void* d_ws, size_t ws_size,
                              hipStream_t stream) {
    const float* x        = (const float*)d_in[0];
    const float* A_w      = (const float*)d_in[1];
    const float* B_w      = (const float*)d_in[2];
    const float* router_w = (const float*)d_in[3];
    const float* ev       = (const float*)d_in[4];
    float* out            = (float*)d_out;

    const int ntok = in_sizes[0] / 4096;     // B*S = 16384
    const int grid = ntok / TPB;             // 4096 blocks
    tmlora_fused<<<grid, 256, 0, stream>>>(x, A_w, B_w, router_w, ev, out);
}